// Round 9
// baseline (72.306 us; speedup 1.0000x reference)
//
#include <hip/hip_runtime.h>

#define B_ 32
#define C_ 64
#define T_ 2048
#define TM 64           // q-columns per block (2 waves x 32)
#define TN 64           // s per tile
#define NT (T_ / TN)

typedef __bf16 bf16x8 __attribute__((ext_vector_type(8)));
typedef float f32x4 __attribute__((ext_vector_type(4)));

__device__ __forceinline__ unsigned cvtpk(float lo, float hi) {
  unsigned r;
  asm("v_cvt_pk_bf16_f32 %0, %1, %2" : "=v"(r) : "v"(lo), "v"(hi));
  return r;
}
__device__ __forceinline__ float exp2v(float x) {
  float r;
  asm("v_exp_f32 %0, %1" : "=v"(r) : "v"(x));  // v_exp_f32 = 2^x
  return r;
}

// K tile: row s (64 x 128B), byte(s,c) = s*128 + ((((c>>3)^(s&7))&7)<<4) + (c&7)*2
// V tile: row c, s at slot sig=(s>>5)*4+((s>>2)&3), byte ((s>>4)&1)*8+(s&3)*2
//   => lane's PV A-frag (cf,m) is ONE b128; element j <-> s = 32m+16(j>>2)+4lh+(j&3)
// Structure: R4's exact kernel (passed, 63.5us) with TM 128->64 (tq loops 4->2,
// the R2/R3-proven register shapes) and grid 512->1024 for 8 waves/CU.

__global__ __launch_bounds__(128, 1) void attn9(const float* __restrict__ qkv,
                                                float* __restrict__ out) {
  __shared__ __align__(16) char smem[2][2][64 * 128];  // [dbuf][K=0/V=1] 32 KB

  const int tid = threadIdx.x;
  // XCD swizzle (bijective, grid 1024): each XCD owns 128 consecutive nb = 4 b's
  const int nb = (blockIdx.x & 7) * 128 + (blockIdx.x >> 3);
  const int b = nb >> 5;
  const int t0 = (nb & 31) * TM;

  const float* qb = qkv + (size_t)b * (3 * C_ * T_);
  const float* kb = qb + C_ * T_;
  const float* vb = qb + 2 * C_ * T_;
  const float qscale = 0.18033688011112042f;  // (1/8) * log2(e), folded into q

  const int l = tid & 63;
  const int w = tid >> 6;     // wave 0..1
  const int lr = l & 15;
  const int lh = l >> 4;      // 0..3
  const int t0w = t0 + w * 32;

  // iter-invariant read offsets (row-XOR drops out: stride 16 rows == 0 mod 8)
  const int offA = lr * 128 + (((lh ^ (lr & 7)) & 7) << 4);        // K half0 / V m=0
  const int offB = lr * 128 + ((((4 + lh) ^ (lr & 7)) & 7) << 4);  // K half1 / V m=1

  // ---- Q fragments (B-operand), 32 t per wave, hoisted ----
  bf16x8 qf[2][2];
#pragma unroll
  for (int tq = 0; tq < 2; ++tq)
#pragma unroll
    for (int h = 0; h < 2; ++h) {
      float qv[8];
#pragma unroll
      for (int j = 0; j < 8; ++j)
        qv[j] = qb[(size_t)(h * 32 + lh * 8 + j) * T_ + t0w + tq * 16 + lr] * qscale;
      union { unsigned u[4]; bf16x8 v; } tmp;
#pragma unroll
      for (int j = 0; j < 4; ++j) tmp.u[j] = cvtpk(qv[2 * j], qv[2 * j + 1]);
      qf[tq][h] = tmp.v;
    }

  // staging: thread owns 8c x 4s  (exact R4 map)
  const int cb = (tid >> 4) * 8;
  const int sq4 = (tid & 15) * 4;
  const int sig = (sq4 >> 5) * 4 + ((sq4 >> 2) & 3);
  const int vh8 = ((sq4 >> 4) & 1) * 8;

  f32x4 kreg[8], vreg[8];
  auto loadK = [&](int s0) {
#pragma unroll
    for (int i = 0; i < 8; ++i)
      kreg[i] = *(const f32x4*)(kb + (size_t)(cb + i) * T_ + s0 + sq4);
  };
  auto writeK = [&](int d) {
    char* Kw = smem[d][0];
#pragma unroll
    for (int j = 0; j < 4; ++j) {  // row s = sq4+j, 8 c's = one b128
      uint4 u;
      u.x = cvtpk(kreg[0][j], kreg[1][j]);
      u.y = cvtpk(kreg[2][j], kreg[3][j]);
      u.z = cvtpk(kreg[4][j], kreg[5][j]);
      u.w = cvtpk(kreg[6][j], kreg[7][j]);
      *(uint4*)(Kw + (sq4 + j) * 128 + ((((cb >> 3) ^ ((sq4 + j) & 7)) & 7) << 4)) = u;
    }
  };
  auto loadV = [&](int s0) {
#pragma unroll
    for (int i = 0; i < 8; ++i)
      vreg[i] = *(const f32x4*)(vb + (size_t)(cb + i) * T_ + s0 + sq4);
  };
  auto writeV = [&](int d) {
    char* Vw = smem[d][1];
#pragma unroll
    for (int i = 0; i < 8; ++i) {  // row c = cb+i, 4 s's = one b64 at its slot-half
      const int c = cb + i;
      uint2 u;
      u.x = cvtpk(vreg[i][0], vreg[i][1]);
      u.y = cvtpk(vreg[i][2], vreg[i][3]);
      *(uint2*)(Vw + c * 128 + (((sig ^ (c & 7)) & 7) << 4) + vh8) = u;
    }
  };

  f32x4 o[4][2];
#pragma unroll
  for (int cf = 0; cf < 4; ++cf)
#pragma unroll
    for (int tq = 0; tq < 2; ++tq) o[cf][tq] = (f32x4){0.f, 0.f, 0.f, 0.f};
  float psum[2] = {0.f, 0.f};

  loadK(0);
  writeK(0);
  loadV(0);
  writeV(0);
  __syncthreads();

  for (int it = 0; it < NT; ++it) {
    const int d = it & 1;
    const bool pf = (it + 1 < NT);
    const int s1 = (it + 1) * TN;
    const char* Kb = smem[d][0];
    const char* Vb = smem[d][1];

    if (pf) loadK(s1);  // K global loads hide under QK^T

    // ---- swapped QK^T: sc[tq][ns] = D[s=16ns+4lh+r][t=t0w+16tq+lr] ----
    f32x4 sc[2][4];
#pragma unroll
    for (int ns = 0; ns < 4; ++ns) {
      const bf16x8 k0 = *(const bf16x8*)(Kb + offA + ns * 2048);
      const bf16x8 k1 = *(const bf16x8*)(Kb + offB + ns * 2048);
#pragma unroll
      for (int tq = 0; tq < 2; ++tq)
        sc[tq][ns] = __builtin_amdgcn_mfma_f32_16x16x32_bf16(
            k0, qf[tq][0], (f32x4){0.f, 0.f, 0.f, 0.f}, 0, 0, 0);
#pragma unroll
      for (int tq = 0; tq < 2; ++tq)
        sc[tq][ns] = __builtin_amdgcn_mfma_f32_16x16x32_bf16(k1, qf[tq][1], sc[tq][ns], 0, 0, 0);
    }

    if (pf) { writeK(d ^ 1); loadV(s1); }  // V loads hide under softmax

    // ---- no-max softmax (exact by shift-invariance; base-2 via folded scale) ----
    unsigned pd[2][2][4];
#pragma unroll
    for (int tq = 0; tq < 2; ++tq) {
      float a0 = 0.f, a1 = 0.f;
#pragma unroll
      for (int ns = 0; ns < 4; ++ns) {
        f32x4 pv;
#pragma unroll
        for (int r = 0; r < 4; ++r) pv[r] = exp2v(sc[tq][ns][r]);
        pd[tq][ns >> 1][(ns & 1) * 2 + 0] = cvtpk(pv[0], pv[1]);
        pd[tq][ns >> 1][(ns & 1) * 2 + 1] = cvtpk(pv[2], pv[3]);
        if (ns & 1) a1 += (pv[0] + pv[1]) + (pv[2] + pv[3]);
        else        a0 += (pv[0] + pv[1]) + (pv[2] + pv[3]);
      }
      psum[tq] += a0 + a1;
    }

    if (pf) writeV(d ^ 1);

    // ---- PV: O^T[c][t] += V x P; V A-frag = one b128 per (cf,m) ----
#pragma unroll
    for (int cf = 0; cf < 4; ++cf) {
      const bf16x8 vA = *(const bf16x8*)(Vb + offA + cf * 2048);
      const bf16x8 vB = *(const bf16x8*)(Vb + offB + cf * 2048);
#pragma unroll
      for (int tq = 0; tq < 2; ++tq) {
        union { unsigned u[4]; bf16x8 v; } p0;
#pragma unroll
        for (int j = 0; j < 4; ++j) p0.u[j] = pd[tq][0][j];
        o[cf][tq] = __builtin_amdgcn_mfma_f32_16x16x32_bf16(vA, p0.v, o[cf][tq], 0, 0, 0);
      }
#pragma unroll
      for (int tq = 0; tq < 2; ++tq) {
        union { unsigned u[4]; bf16x8 v; } p1;
#pragma unroll
        for (int j = 0; j < 4; ++j) p1.u[j] = pd[tq][1][j];
        o[cf][tq] = __builtin_amdgcn_mfma_f32_16x16x32_bf16(vB, p1.v, o[cf][tq], 0, 0, 0);
      }
    }
    __syncthreads();
  }

  // ---- epilogue: denominators across lh lanes; 2 shuffles, store ----
  float inv[2];
#pragma unroll
  for (int tq = 0; tq < 2; ++tq) {
    float s = psum[tq];
    s += __shfl_xor(s, 16, 64);
    s += __shfl_xor(s, 32, 64);
    inv[tq] = 1.0f / s;
  }
  float* ob = out + (size_t)b * (C_ * T_);
#pragma unroll
  for (int cf = 0; cf < 4; ++cf)
#pragma unroll
    for (int tq = 0; tq < 2; ++tq)
#pragma unroll
      for (int r = 0; r < 4; ++r)
        ob[(size_t)(cf * 16 + lh * 4 + r) * T_ + t0w + tq * 16 + lr] = o[cf][tq][r] * inv[tq];
}

extern "C" void kernel_launch(void* const* d_in, const int* in_sizes, int n_in,
                              void* d_out, int out_size, void* d_ws, size_t ws_size,
                              hipStream_t stream) {
  const float* qkv = (const float*)d_in[0];
  float* out = (float*)d_out;
  dim3 grid((T_ / TM) * B_);
  dim3 block(128);
  hipLaunchKernelGGL(attn9, grid, block, 0, stream, qkv, out);
}